// Round 1
// baseline (1215.231 us; speedup 1.0000x reference)
//
#include <hip/hip_runtime.h>

// Fused Inception dilated-causal-conv stack for MI355X (gfx950).
// x:(64,8,16384) f32 -> out:(64,96,16378) f32, channels [m7|m10|m15].
//
// Per block: one batch x one 128-position output tile, 256 threads.
//   stage0: x halo tile -> LDS (xs)
//   stage1: conv1 (K=3,d=1) for 3 branches -> 42 LDS rows (as)
//   stage2: conv2 (K=3,d=2): b7 (=m7) -> global, b10/b15 -> 42 LDS rows (bs)
//   stage3: conv3 (d=4, K=2/K=3 with causal left pad) -> global
// Weights live in registers (one output channel per thread).

namespace {
constexpr int TB  = 128;                 // output positions per tile
constexpr int NB  = 64, NC = 8, NL = 16384, NLO = NL - 6;
constexpr int NTILES = (NLO + TB - 1) / TB;   // 128
constexpr int XS_STR = 152;              // x rows: p in [0,152) <-> global i0-8+p
constexpr int AS_STR = 144;              // a rows: 144 computed positions
constexpr int BS_STR = 136;              // b rows: 136 positions
constexpr int XS_BASE = 42 * AS_STR;     // 6048 floats
constexpr int BS_BASE = XS_BASE;         // bs overlays xs (dead after stage1)
constexpr int LDS_FLOATS = BS_BASE + 42 * BS_STR;  // 11760 floats = 47040 B -> 3 blocks/CU
}

__global__ __launch_bounds__(256, 3)
void inception_fused(const float* __restrict__ x,
                     const float* __restrict__ w7_1,  const float* __restrict__ w7_3,
                     const float* __restrict__ w10_1, const float* __restrict__ w10_3,
                     const float* __restrict__ w10_5,
                     const float* __restrict__ w15_1, const float* __restrict__ w15_3,
                     const float* __restrict__ w15_5,
                     float* __restrict__ out)
{
    __shared__ __align__(16) float lds[LDS_FLOATS];
    const int tid = threadIdx.x;
    const int i0  = blockIdx.x * TB;
    const int bb  = blockIdx.y;

    // ---------------- stage 0: stage x tile (zero-padded) ----------------
    {
        constexpr int QPR = XS_STR / 4;              // 38 float4 per row
        for (int idx = tid; idx < NC * QPR; idx += 256) {
            const int c = idx / QPR;
            const int p = (idx - c * QPR) * 4;
            const int g = i0 - 8 + p;                // global x position
            const float* xrow = x + ((size_t)bb * NC + c) * NL;
            float4 v;
            if (g >= 0 && g <= NL - 4) {
                v = *reinterpret_cast<const float4*>(xrow + g);
            } else {
                v.x = ((unsigned)(g + 0) < (unsigned)NL) ? xrow[g + 0] : 0.f;
                v.y = ((unsigned)(g + 1) < (unsigned)NL) ? xrow[g + 1] : 0.f;
                v.z = ((unsigned)(g + 2) < (unsigned)NL) ? xrow[g + 2] : 0.f;
                v.w = ((unsigned)(g + 3) < (unsigned)NL) ? xrow[g + 3] : 0.f;
            }
            *reinterpret_cast<float4*>(&lds[XS_BASE + c * XS_STR + p]) = v;
        }
    }
    __syncthreads();

    // ---------------- stage 1: conv1 K=3 d=1, 42 channels ----------------
    // a[ch][q] <-> global position i0-8+q, q in [0,144)
    if (tid < 252) {
        const int ch = tid / 6;                      // 0..41
        const int s  = tid - ch * 6;
        const int br = ch / 14, oc = ch - br * 14;
        const float* w1 = (br == 0 ? w7_1 : (br == 1 ? w10_1 : w15_1)) + oc * 24;
        float wr[24];
        #pragma unroll
        for (int j = 0; j < 6; ++j) {
            float4 t = *reinterpret_cast<const float4*>(w1 + 4 * j);
            wr[4*j+0] = t.x; wr[4*j+1] = t.y; wr[4*j+2] = t.z; wr[4*j+3] = t.w;
        }
        for (int o = s; o < 18; o += 6) {            // 3 octs each
            const int p0 = o * 8;
            float acc[8] = {0,0,0,0,0,0,0,0};
            #pragma unroll
            for (int c = 0; c < NC; ++c) {
                const float* row = &lds[XS_BASE + c * XS_STR + p0];
                float win[12];
                #pragma unroll
                for (int h = 0; h < 3; ++h) {
                    float4 t = *reinterpret_cast<const float4*>(row + 4 * h);
                    win[4*h+0] = t.x; win[4*h+1] = t.y; win[4*h+2] = t.z; win[4*h+3] = t.w;
                }
                #pragma unroll
                for (int k = 0; k < 3; ++k)
                    #pragma unroll
                    for (int j = 0; j < 8; ++j)
                        acc[j] = fmaf(win[j + k], wr[c * 3 + k], acc[j]);
            }
            float4 v0, v1;
            v0.x = fmaxf(acc[0], 0.f); v0.y = fmaxf(acc[1], 0.f);
            v0.z = fmaxf(acc[2], 0.f); v0.w = fmaxf(acc[3], 0.f);
            v1.x = fmaxf(acc[4], 0.f); v1.y = fmaxf(acc[5], 0.f);
            v1.z = fmaxf(acc[6], 0.f); v1.w = fmaxf(acc[7], 0.f);
            float* arow = &lds[ch * AS_STR + p0];
            *reinterpret_cast<float4*>(arow)     = v0;
            *reinterpret_cast<float4*>(arow + 4) = v1;
        }
    }
    __syncthreads();

    // ---------------- stage 2: conv2 K=3 d=2, 74 channels ----------------
    if (tid < 222) {
        const int ch = tid / 3;                      // 0..73
        const int s  = tid - ch * 3;
        const float* w2; int arow0;
        if (ch < 32)      { w2 = w7_3  + ch * 42;        arow0 = 0;  }
        else if (ch < 53) { w2 = w10_3 + (ch - 32) * 42; arow0 = 14; }
        else              { w2 = w15_3 + (ch - 53) * 42; arow0 = 28; }
        float wr[42];
        #pragma unroll
        for (int j = 0; j < 21; ++j) {
            float2 t = *reinterpret_cast<const float2*>(w2 + 2 * j);
            wr[2*j] = t.x; wr[2*j+1] = t.y;
        }
        if (ch < 32) {
            // m7 final output channel ch: outputs i = i0-8+p, p in [8,136)
            float* orow = out + ((size_t)bb * 96 + ch) * NLO;
            for (int o = s; o < 16; o += 3) {
                const int p0 = 8 + o * 8;
                float acc[8] = {0,0,0,0,0,0,0,0};
                #pragma unroll
                for (int c = 0; c < 14; ++c) {
                    const float* row = &lds[(arow0 + c) * AS_STR + p0];
                    float win[12];
                    #pragma unroll
                    for (int h = 0; h < 3; ++h) {
                        float4 t = *reinterpret_cast<const float4*>(row + 4 * h);
                        win[4*h+0] = t.x; win[4*h+1] = t.y; win[4*h+2] = t.z; win[4*h+3] = t.w;
                    }
                    #pragma unroll
                    for (int k = 0; k < 3; ++k)
                        #pragma unroll
                        for (int j = 0; j < 8; ++j)
                            acc[j] = fmaf(win[j + 2 * k], wr[c * 3 + k], acc[j]);
                }
                const int ib = i0 + p0 - 8;
                if (ib + 7 < NLO) {
                    #pragma unroll
                    for (int h = 0; h < 4; ++h) {
                        float2 v;
                        v.x = fmaxf(acc[2*h],   0.f);
                        v.y = fmaxf(acc[2*h+1], 0.f);
                        *reinterpret_cast<float2*>(orow + ib + 2 * h) = v;
                    }
                } else {
                    #pragma unroll
                    for (int j = 0; j < 8; ++j)
                        if (ib + j < NLO) orow[ib + j] = fmaxf(acc[j], 0.f);
                }
            }
        } else {
            const int bc = ch - 32;                  // bs row 0..41 (b10: 0..20, b15: 21..41)
            for (int o = s; o < 17; o += 3) {
                const int p0 = o * 8;
                float acc[8] = {0,0,0,0,0,0,0,0};
                #pragma unroll
                for (int c = 0; c < 14; ++c) {
                    const float* row = &lds[(arow0 + c) * AS_STR + p0];
                    float win[12];
                    #pragma unroll
                    for (int h = 0; h < 3; ++h) {
                        float4 t = *reinterpret_cast<const float4*>(row + 4 * h);
                        win[4*h+0] = t.x; win[4*h+1] = t.y; win[4*h+2] = t.z; win[4*h+3] = t.w;
                    }
                    #pragma unroll
                    for (int k = 0; k < 3; ++k)
                        #pragma unroll
                        for (int j = 0; j < 8; ++j)
                            acc[j] = fmaf(win[j + 2 * k], wr[c * 3 + k], acc[j]);
                }
                // relu + causal left-pad: b[global j<0] must be exactly 0
                const int jg = i0 - 8 + p0;
                float r[8];
                #pragma unroll
                for (int j = 0; j < 8; ++j)
                    r[j] = (jg + j >= 0) ? fmaxf(acc[j], 0.f) : 0.f;
                float* brow = &lds[BS_BASE + bc * BS_STR + p0];
                float4 v0, v1;
                v0.x = r[0]; v0.y = r[1]; v0.z = r[2]; v0.w = r[3];
                v1.x = r[4]; v1.y = r[5]; v1.z = r[6]; v1.w = r[7];
                *reinterpret_cast<float4*>(brow)     = v0;
                *reinterpret_cast<float4*>(brow + 4) = v1;
            }
        }
    }
    __syncthreads();

    // ---------------- stage 3: conv3 d=4 (m10 K=2, m15 K=3) ----------------
    {
        const int ch = tid >> 2;                     // 0..63
        const int s  = tid & 3;
        const bool is10 = (ch < 32);
        float wr[63];
        int outch;
        if (is10) {
            const float* w3 = w10_5 + ch * 42;
            #pragma unroll
            for (int j = 0; j < 21; ++j) {
                float2 t = *reinterpret_cast<const float2*>(w3 + 2 * j);
                wr[2*j] = t.x; wr[2*j+1] = t.y;
            }
            outch = 32 + ch;
        } else {
            const float* w3 = w15_5 + (ch - 32) * 63;
            #pragma unroll
            for (int j = 0; j < 63; ++j) wr[j] = w3[j];
            outch = 64 + (ch - 32);
        }
        float* orow = out + ((size_t)bb * 96 + outch) * NLO;
        for (int o = s; o < 16; o += 4) {            // 4 octs each
            const int t0 = o * 8;
            float acc[8] = {0,0,0,0,0,0,0,0};
            if (is10) {
                // m10[i] = b10[i-4]*w0 + b10[i]*w1 ; bs idx p = t+4, t+8
                #pragma unroll
                for (int c = 0; c < 21; ++c) {
                    const float* row = &lds[BS_BASE + c * BS_STR + t0 + 4];
                    float win[12];
                    #pragma unroll
                    for (int h = 0; h < 3; ++h) {
                        float4 t = *reinterpret_cast<const float4*>(row + 4 * h);
                        win[4*h+0] = t.x; win[4*h+1] = t.y; win[4*h+2] = t.z; win[4*h+3] = t.w;
                    }
                    #pragma unroll
                    for (int j = 0; j < 8; ++j)
                        acc[j] = fmaf(win[j], wr[2*c],
                                 fmaf(win[j + 4], wr[2*c+1], acc[j]));
                }
            } else {
                // m15[i] = b15[i-8]*w0 + b15[i-4]*w1 + b15[i]*w2 ; p = t, t+4, t+8
                #pragma unroll
                for (int c = 0; c < 21; ++c) {
                    const float* row = &lds[BS_BASE + (21 + c) * BS_STR + t0];
                    float win[16];
                    #pragma unroll
                    for (int h = 0; h < 4; ++h) {
                        float4 t = *reinterpret_cast<const float4*>(row + 4 * h);
                        win[4*h+0] = t.x; win[4*h+1] = t.y; win[4*h+2] = t.z; win[4*h+3] = t.w;
                    }
                    #pragma unroll
                    for (int j = 0; j < 8; ++j)
                        acc[j] = fmaf(win[j],     wr[3*c],
                                 fmaf(win[j + 4], wr[3*c+1],
                                 fmaf(win[j + 8], wr[3*c+2], acc[j])));
                }
            }
            const int ib = i0 + t0;
            if (ib + 7 < NLO) {
                #pragma unroll
                for (int h = 0; h < 4; ++h) {
                    float2 v;
                    v.x = fmaxf(acc[2*h],   0.f);
                    v.y = fmaxf(acc[2*h+1], 0.f);
                    *reinterpret_cast<float2*>(orow + ib + 2 * h) = v;
                }
            } else {
                #pragma unroll
                for (int j = 0; j < 8; ++j)
                    if (ib + j < NLO) orow[ib + j] = fmaxf(acc[j], 0.f);
            }
        }
    }
}

extern "C" void kernel_launch(void* const* d_in, const int* in_sizes, int n_in,
                              void* d_out, int out_size, void* d_ws, size_t ws_size,
                              hipStream_t stream) {
    dim3 grid(NTILES, NB);
    inception_fused<<<grid, 256, 0, stream>>>(
        (const float*)d_in[0],
        (const float*)d_in[1], (const float*)d_in[2],
        (const float*)d_in[3], (const float*)d_in[4], (const float*)d_in[5],
        (const float*)d_in[6], (const float*)d_in[7], (const float*)d_in[8],
        (float*)d_out);
}

// Round 2
// 828.947 us; speedup vs baseline: 1.4660x; 1.4660x over previous
//
#include <hip/hip_runtime.h>

// Fused Inception dilated-causal-conv stack for MI355X (gfx950).
// x:(64,8,16384) f32 -> out:(64,96,16378) f32, channels [m7|m10|m15].
//
// Per block: one batch x one 128-position output tile, 256 threads.
//   stage0: x halo tile -> LDS (xs)
//   stage1: conv1 (K=3,d=1) for 3 branches -> 42 LDS rows (as)
//   stage2: conv2 (K=3,d=2): m7 -> registers, b10/b15 -> 42 LDS rows (bs)
//   stage3: conv3 (d=4, K=2/K=3, causal left pad) -> registers
// All global output writes go through LDS staging and are emitted as
// lane-contiguous float2 stores (wave = 512B contiguous, full 64B lines)
// to avoid the 4.3x write amplification / partial-line RMW seen in R1.

namespace {
constexpr int TB  = 128;                 // output positions per tile
constexpr int NB  = 64, NC = 8, NL = 16384, NLO = NL - 6;
constexpr int NTILES = (NLO + TB - 1) / TB;   // 128
constexpr int XS_STR = 152;              // x rows: p in [0,152) <-> global i0-8+p
constexpr int AS_STR = 144;              // a rows: 144 computed positions
constexpr int BS_STR = 136;              // b rows: 136 positions
constexpr int MS_STR = 132;              // output staging stride (bank swizzle)
constexpr int AS_BASE = 0;
constexpr int XS_BASE = 42 * AS_STR;     // 6048 floats
constexpr int BS_BASE = XS_BASE;         // bs overlays xs (dead after stage1)
constexpr int LDS_FLOATS = BS_BASE + 42 * BS_STR;  // 11760 floats = 47040 B -> 3 blocks/CU
// staging reuse: m7 & m10 as [32][MS_STR] at AS_BASE (4224 <= 6048 ok),
//                m15      as [32][MS_STR] at BS_BASE (4224 <= 5712 ok)
}

__global__ __launch_bounds__(256, 3)
void inception_fused(const float* __restrict__ x,
                     const float* __restrict__ w7_1,  const float* __restrict__ w7_3,
                     const float* __restrict__ w10_1, const float* __restrict__ w10_3,
                     const float* __restrict__ w10_5,
                     const float* __restrict__ w15_1, const float* __restrict__ w15_3,
                     const float* __restrict__ w15_5,
                     float* __restrict__ out)
{
    __shared__ __align__(16) float lds[LDS_FLOATS];
    const int tid = threadIdx.x;
    const int i0  = blockIdx.x * TB;
    const int bb  = blockIdx.y;

    // ---------------- stage 0: stage x tile (zero-padded) ----------------
    {
        constexpr int QPR = XS_STR / 4;              // 38 float4 per row
        for (int idx = tid; idx < NC * QPR; idx += 256) {
            const int c = idx / QPR;
            const int p = (idx - c * QPR) * 4;
            const int g = i0 - 8 + p;                // global x position
            const float* xrow = x + ((size_t)bb * NC + c) * NL;
            float4 v;
            if (g >= 0 && g <= NL - 4) {
                v = *reinterpret_cast<const float4*>(xrow + g);
            } else {
                v.x = ((unsigned)(g + 0) < (unsigned)NL) ? xrow[g + 0] : 0.f;
                v.y = ((unsigned)(g + 1) < (unsigned)NL) ? xrow[g + 1] : 0.f;
                v.z = ((unsigned)(g + 2) < (unsigned)NL) ? xrow[g + 2] : 0.f;
                v.w = ((unsigned)(g + 3) < (unsigned)NL) ? xrow[g + 3] : 0.f;
            }
            *reinterpret_cast<float4*>(&lds[XS_BASE + c * XS_STR + p]) = v;
        }
    }
    __syncthreads();

    // ---------------- stage 1: conv1 K=3 d=1, 42 channels ----------------
    // a[ch][q] <-> global position i0-8+q, q in [0,144)
    if (tid < 252) {
        const int ch = tid / 6;                      // 0..41
        const int s  = tid - ch * 6;
        const int br = ch / 14, oc = ch - br * 14;
        const float* w1 = (br == 0 ? w7_1 : (br == 1 ? w10_1 : w15_1)) + oc * 24;
        float wr[24];
        #pragma unroll
        for (int j = 0; j < 6; ++j) {
            float4 t = *reinterpret_cast<const float4*>(w1 + 4 * j);
            wr[4*j+0] = t.x; wr[4*j+1] = t.y; wr[4*j+2] = t.z; wr[4*j+3] = t.w;
        }
        for (int o = s; o < 18; o += 6) {            // 3 octs each
            const int p0 = o * 8;
            float acc[8] = {0,0,0,0,0,0,0,0};
            #pragma unroll
            for (int c = 0; c < NC; ++c) {
                const float* row = &lds[XS_BASE + c * XS_STR + p0];
                float win[12];
                #pragma unroll
                for (int h = 0; h < 3; ++h) {
                    float4 t = *reinterpret_cast<const float4*>(row + 4 * h);
                    win[4*h+0] = t.x; win[4*h+1] = t.y; win[4*h+2] = t.z; win[4*h+3] = t.w;
                }
                #pragma unroll
                for (int k = 0; k < 3; ++k)
                    #pragma unroll
                    for (int j = 0; j < 8; ++j)
                        acc[j] = fmaf(win[j + k], wr[c * 3 + k], acc[j]);
            }
            float4 v0, v1;
            v0.x = fmaxf(acc[0], 0.f); v0.y = fmaxf(acc[1], 0.f);
            v0.z = fmaxf(acc[2], 0.f); v0.w = fmaxf(acc[3], 0.f);
            v1.x = fmaxf(acc[4], 0.f); v1.y = fmaxf(acc[5], 0.f);
            v1.z = fmaxf(acc[6], 0.f); v1.w = fmaxf(acc[7], 0.f);
            float* arow = &lds[AS_BASE + ch * AS_STR + p0];
            *reinterpret_cast<float4*>(arow)     = v0;
            *reinterpret_cast<float4*>(arow + 4) = v1;
        }
    }
    __syncthreads();

    // ---------------- stage 2: conv2 K=3 d=2 ----------------
    // threads [0,128): m7 channel ch=tid>>2, 4 octs -> registers
    // threads [128,254): b10/b15 channel, ~6 octs -> BS rows
    float m7r[4][8];
    if (tid < 128) {
        const int ch = tid >> 2;
        const int s  = tid & 3;
        const float* w2 = w7_3 + ch * 42;
        float wr[42];
        #pragma unroll
        for (int j = 0; j < 21; ++j) {
            float2 t = *reinterpret_cast<const float2*>(w2 + 2 * j);
            wr[2*j] = t.x; wr[2*j+1] = t.y;
        }
        #pragma unroll
        for (int k = 0; k < 4; ++k) {
            const int p0 = 8 + (s + 4 * k) * 8;      // tile pos = p0-8
            float acc[8] = {0,0,0,0,0,0,0,0};
            #pragma unroll
            for (int c = 0; c < 14; ++c) {
                const float* row = &lds[AS_BASE + c * AS_STR + p0];
                float win[12];
                #pragma unroll
                for (int h = 0; h < 3; ++h) {
                    float4 t = *reinterpret_cast<const float4*>(row + 4 * h);
                    win[4*h+0] = t.x; win[4*h+1] = t.y; win[4*h+2] = t.z; win[4*h+3] = t.w;
                }
                #pragma unroll
                for (int kk = 0; kk < 3; ++kk)
                    #pragma unroll
                    for (int j = 0; j < 8; ++j)
                        acc[j] = fmaf(win[j + 2 * kk], wr[c * 3 + kk], acc[j]);
            }
            #pragma unroll
            for (int j = 0; j < 8; ++j) m7r[k][j] = fmaxf(acc[j], 0.f);
        }
    } else if (tid < 254) {
        const int t2 = tid - 128;
        const int bc = t2 / 3;                       // 0..41
        const int s  = t2 - bc * 3;
        const float* w2 = (bc < 21) ? (w10_3 + bc * 42) : (w15_3 + (bc - 21) * 42);
        const int arow0 = (bc < 21) ? 14 : 28;
        float wr[42];
        #pragma unroll
        for (int j = 0; j < 21; ++j) {
            float2 t = *reinterpret_cast<const float2*>(w2 + 2 * j);
            wr[2*j] = t.x; wr[2*j+1] = t.y;
        }
        for (int o = s; o < 17; o += 3) {            // 5-6 octs each
            const int p0 = o * 8;
            float acc[8] = {0,0,0,0,0,0,0,0};
            #pragma unroll
            for (int c = 0; c < 14; ++c) {
                const float* row = &lds[AS_BASE + (arow0 + c) * AS_STR + p0];
                float win[12];
                #pragma unroll
                for (int h = 0; h < 3; ++h) {
                    float4 t = *reinterpret_cast<const float4*>(row + 4 * h);
                    win[4*h+0] = t.x; win[4*h+1] = t.y; win[4*h+2] = t.z; win[4*h+3] = t.w;
                }
                #pragma unroll
                for (int kk = 0; kk < 3; ++kk)
                    #pragma unroll
                    for (int j = 0; j < 8; ++j)
                        acc[j] = fmaf(win[j + 2 * kk], wr[c * 3 + kk], acc[j]);
            }
            // relu + causal left-pad: b[global j<0] must be exactly 0
            const int jg = i0 - 8 + p0;
            float* brow = &lds[BS_BASE + bc * BS_STR + p0];
            float4 v0, v1;
            v0.x = (jg + 0 >= 0) ? fmaxf(acc[0], 0.f) : 0.f;
            v0.y = (jg + 1 >= 0) ? fmaxf(acc[1], 0.f) : 0.f;
            v0.z = (jg + 2 >= 0) ? fmaxf(acc[2], 0.f) : 0.f;
            v0.w = (jg + 3 >= 0) ? fmaxf(acc[3], 0.f) : 0.f;
            v1.x = (jg + 4 >= 0) ? fmaxf(acc[4], 0.f) : 0.f;
            v1.y = (jg + 5 >= 0) ? fmaxf(acc[5], 0.f) : 0.f;
            v1.z = (jg + 6 >= 0) ? fmaxf(acc[6], 0.f) : 0.f;
            v1.w = (jg + 7 >= 0) ? fmaxf(acc[7], 0.f) : 0.f;
            *reinterpret_cast<float4*>(brow)     = v0;
            *reinterpret_cast<float4*>(brow + 4) = v1;
        }
    }
    __syncthreads();

    // ------------- stage m7 registers -> AS region [32][MS_STR] -------------
    if (tid < 128) {
        const int ch = tid >> 2;
        const int s  = tid & 3;
        #pragma unroll
        for (int k = 0; k < 4; ++k) {
            float* mrow = &lds[AS_BASE + ch * MS_STR + (s + 4 * k) * 8];
            float4 v0, v1;
            v0.x = m7r[k][0]; v0.y = m7r[k][1]; v0.z = m7r[k][2]; v0.w = m7r[k][3];
            v1.x = m7r[k][4]; v1.y = m7r[k][5]; v1.z = m7r[k][6]; v1.w = m7r[k][7];
            *reinterpret_cast<float4*>(mrow)     = v0;
            *reinterpret_cast<float4*>(mrow + 4) = v1;
        }
    }
    __syncthreads();

    // ------------- copy m7 -> global (coalesced float2) -------------
    {
        #pragma unroll
        for (int k = 0; k < 8; ++k) {
            const int f  = k * 256 + tid;            // [0, 2048)
            const int ch = f >> 6;                   // 0..31
            const int q  = f & 63;
            const int gpos = i0 + 2 * q;
            const float2 v = *reinterpret_cast<const float2*>(&lds[AS_BASE + ch * MS_STR + 2 * q]);
            float* orow = out + ((size_t)bb * 96 + ch) * NLO;
            if (gpos + 1 < NLO) {
                *reinterpret_cast<float2*>(orow + gpos) = v;
            } else if (gpos < NLO) {
                orow[gpos] = v.x;
            }
        }
    }

    // ---------------- stage 3: conv3 d=4 (m10 K=2, m15 K=3) -> regs ----------------
    float m3r[4][8];
    {
        const int ch = tid >> 2;                     // 0..63
        const int s  = tid & 3;
        const bool is10 = (ch < 32);
        float wr[63];
        if (is10) {
            const float* w3 = w10_5 + ch * 42;
            #pragma unroll
            for (int j = 0; j < 21; ++j) {
                float2 t = *reinterpret_cast<const float2*>(w3 + 2 * j);
                wr[2*j] = t.x; wr[2*j+1] = t.y;
            }
        } else {
            const float* w3 = w15_5 + (ch - 32) * 63;
            #pragma unroll
            for (int j = 0; j < 63; ++j) wr[j] = w3[j];
        }
        #pragma unroll
        for (int k = 0; k < 4; ++k) {
            const int t0 = (s + 4 * k) * 8;
            float acc[8] = {0,0,0,0,0,0,0,0};
            if (is10) {
                // m10[i] = b10[i-4]*w0 + b10[i]*w1 ; bs idx p = t+4, t+8
                #pragma unroll
                for (int c = 0; c < 21; ++c) {
                    const float* row = &lds[BS_BASE + c * BS_STR + t0 + 4];
                    float win[12];
                    #pragma unroll
                    for (int h = 0; h < 3; ++h) {
                        float4 t = *reinterpret_cast<const float4*>(row + 4 * h);
                        win[4*h+0] = t.x; win[4*h+1] = t.y; win[4*h+2] = t.z; win[4*h+3] = t.w;
                    }
                    #pragma unroll
                    for (int j = 0; j < 8; ++j)
                        acc[j] = fmaf(win[j], wr[2*c],
                                 fmaf(win[j + 4], wr[2*c+1], acc[j]));
                }
            } else {
                // m15[i] = b15[i-8]*w0 + b15[i-4]*w1 + b15[i]*w2 ; p = t, t+4, t+8
                #pragma unroll
                for (int c = 0; c < 21; ++c) {
                    const float* row = &lds[BS_BASE + (21 + c) * BS_STR + t0];
                    float win[16];
                    #pragma unroll
                    for (int h = 0; h < 4; ++h) {
                        float4 t = *reinterpret_cast<const float4*>(row + 4 * h);
                        win[4*h+0] = t.x; win[4*h+1] = t.y; win[4*h+2] = t.z; win[4*h+3] = t.w;
                    }
                    #pragma unroll
                    for (int j = 0; j < 8; ++j)
                        acc[j] = fmaf(win[j],     wr[3*c],
                                 fmaf(win[j + 4], wr[3*c+1],
                                 fmaf(win[j + 8], wr[3*c+2], acc[j])));
                }
            }
            #pragma unroll
            for (int j = 0; j < 8; ++j) m3r[k][j] = fmaxf(acc[j], 0.f);
        }
    }
    __syncthreads();   // all m7-copy LDS reads + stage3 BS reads done

    // ------------- stage m10 -> AS region, m15 -> BS region -------------
    {
        const int ch = tid >> 2;
        const int s  = tid & 3;
        const int sbase = (ch < 32) ? (AS_BASE + ch * MS_STR)
                                    : (BS_BASE + (ch - 32) * MS_STR);
        #pragma unroll
        for (int k = 0; k < 4; ++k) {
            float* mrow = &lds[sbase + (s + 4 * k) * 8];
            float4 v0, v1;
            v0.x = m3r[k][0]; v0.y = m3r[k][1]; v0.z = m3r[k][2]; v0.w = m3r[k][3];
            v1.x = m3r[k][4]; v1.y = m3r[k][5]; v1.z = m3r[k][6]; v1.w = m3r[k][7];
            *reinterpret_cast<float4*>(mrow)     = v0;
            *reinterpret_cast<float4*>(mrow + 4) = v1;
        }
    }
    __syncthreads();

    // ------------- copy m10+m15 -> global (coalesced float2) -------------
    {
        #pragma unroll
        for (int k = 0; k < 16; ++k) {
            const int f  = k * 256 + tid;            // [0, 4096)
            const int c6 = f >> 6;                   // 0..63
            const int q  = f & 63;
            const int gpos = i0 + 2 * q;
            const int src = (c6 < 32) ? (AS_BASE + c6 * MS_STR + 2 * q)
                                      : (BS_BASE + (c6 - 32) * MS_STR + 2 * q);
            const float2 v = *reinterpret_cast<const float2*>(&lds[src]);
            float* orow = out + ((size_t)bb * 96 + 32 + c6) * NLO;
            if (gpos + 1 < NLO) {
                *reinterpret_cast<float2*>(orow + gpos) = v;
            } else if (gpos < NLO) {
                orow[gpos] = v.x;
            }
        }
    }
}

extern "C" void kernel_launch(void* const* d_in, const int* in_sizes, int n_in,
                              void* d_out, int out_size, void* d_ws, size_t ws_size,
                              hipStream_t stream) {
    dim3 grid(NTILES, NB);
    inception_fused<<<grid, 256, 0, stream>>>(
        (const float*)d_in[0],
        (const float*)d_in[1], (const float*)d_in[2],
        (const float*)d_in[3], (const float*)d_in[4], (const float*)d_in[5],
        (const float*)d_in[6], (const float*)d_in[7], (const float*)d_in[8],
        (float*)d_out);
}